// Round 9
// baseline (638.282 us; speedup 1.0000x reference)
//
#include <hip/hip_runtime.h>
#include <stdint.h>

#define BATCH 128
#define SEQL  512
#define FDIM  768
#define CTAGS 52
#define START_IDX 50
#define STOP_IDX  51
#define NEG_INF (-3.0e38f)

// ---------------------------------------------------------------------------
// K0: transpose W [52][768] -> WT [768][52]. Tiny, runs once.
// ---------------------------------------------------------------------------
__global__ __launch_bounds__(256) void wtrans(
    const float* __restrict__ W, float* __restrict__ WT)
{
    int idx = blockIdx.x * 256 + threadIdx.x;
    if (idx < FDIM * CTAGS) {
        int k = idx / CTAGS;
        int c = idx - k * CTAGS;
        WT[idx] = W[(size_t)c * FDIM + k];
    }
}

// ---------------------------------------------------------------------------
// K1: emission GEMM v5. Same operand routing as gemm4 (W scalar s_load path,
// F via LDS padded stride 33), but 2 rows x 13 cols per thread: the 52
// s_load floats per 4-k group now feed 104 FMAs (2x density). Block covers
// 128 rows x 52 cols; grid 512 -> 2 blocks/CU, 2 waves/SIMD.
// ---------------------------------------------------------------------------
#define BK32 32
#define LPAD 33

__global__ __launch_bounds__(256) void emit_gemm5(
    const float* __restrict__ F, const float* __restrict__ WT,
    const float* __restrict__ bias, float* __restrict__ emit)
{
    __shared__ float buf[2][128 * LPAD];   // 2 x 16.9 KB

    const int tid  = threadIdx.x;
    const int lane = tid & 63;
    const int cg   = __builtin_amdgcn_readfirstlane(tid >> 6);
    const int c0   = cg * 13;
    const int row0 = blockIdx.x * 128;

    // staging map: thread covers rows r0, r0+32, r0+64, r0+96, k-slot s0
    const int r0 = tid >> 3;          // 0..31
    const int s0 = tid & 7;           // 0..7
    const float* g0 = F + (size_t)(row0 + r0) * FDIM + s0 * 4;
    const float* g1 = g0 + (size_t)32 * FDIM;
    const float* g2 = g0 + (size_t)64 * FDIM;
    const float* g3 = g0 + (size_t)96 * FDIM;
    const int i0 = (r0      ) * LPAD + s0 * 4;
    const int i1 = (r0 + 32 ) * LPAD + s0 * 4;
    const int i2 = (r0 + 64 ) * LPAD + s0 * 4;
    const int i3 = (r0 + 96 ) * LPAD + s0 * 4;

    float acc0[13], acc1[13];
#pragma unroll
    for (int c = 0; c < 13; ++c) { acc0[c] = bias[c0 + c]; acc1[c] = acc0[c]; }

#define STG(dst, v) { dst[0]=v.x; dst[1]=v.y; dst[2]=v.z; dst[3]=v.w; }
    {
        float4 a0 = *(const float4*)g0; float4 a1 = *(const float4*)g1;
        float4 a2 = *(const float4*)g2; float4 a3 = *(const float4*)g3;
        STG((&buf[0][i0]), a0); STG((&buf[0][i1]), a1);
        STG((&buf[0][i2]), a2); STG((&buf[0][i3]), a3);
    }
    __syncthreads();

    int cur = 0;
    for (int t = 0; t < FDIM / BK32; ++t) {
        const int k0 = t * BK32;

        float4 b0, b1, b2, b3;
        if (t < FDIM / BK32 - 1) {
            b0 = *(const float4*)(g0 + k0 + BK32);
            b1 = *(const float4*)(g1 + k0 + BK32);
            b2 = *(const float4*)(g2 + k0 + BK32);
            b3 = *(const float4*)(g3 + k0 + BK32);
        }

        const float* fb0 = &buf[cur][lane * LPAD];
        const float* fb1 = &buf[cur][(lane + 64) * LPAD];
#pragma unroll
        for (int kk = 0; kk < BK32; kk += 4) {
            float f00 = fb0[kk + 0], f01 = fb0[kk + 1];
            float f02 = fb0[kk + 2], f03 = fb0[kk + 3];
            float f10 = fb1[kk + 0], f11 = fb1[kk + 1];
            float f12 = fb1[kk + 2], f13 = fb1[kk + 3];
            const float* w0 = WT + (size_t)(k0 + kk + 0) * CTAGS + c0;
            const float* w1 = WT + (size_t)(k0 + kk + 1) * CTAGS + c0;
            const float* w2 = WT + (size_t)(k0 + kk + 2) * CTAGS + c0;
            const float* w3 = WT + (size_t)(k0 + kk + 3) * CTAGS + c0;
#pragma unroll
            for (int c = 0; c < 13; ++c) {
                float wa = w0[c], wb = w1[c], wc = w2[c], wd = w3[c];
                acc0[c] = fmaf(f00, wa, acc0[c]);
                acc0[c] = fmaf(f01, wb, acc0[c]);
                acc0[c] = fmaf(f02, wc, acc0[c]);
                acc0[c] = fmaf(f03, wd, acc0[c]);
                acc1[c] = fmaf(f10, wa, acc1[c]);
                acc1[c] = fmaf(f11, wb, acc1[c]);
                acc1[c] = fmaf(f12, wc, acc1[c]);
                acc1[c] = fmaf(f13, wd, acc1[c]);
            }
        }

        if (t < FDIM / BK32 - 1) {
            const int nb = cur ^ 1;
            STG((&buf[nb][i0]), b0); STG((&buf[nb][i1]), b1);
            STG((&buf[nb][i2]), b2); STG((&buf[nb][i3]), b3);
        }
        __syncthreads();
        cur ^= 1;
    }
#undef STG

    float* eo0 = emit + (size_t)(row0 + lane)      * CTAGS + c0;
    float* eo1 = emit + (size_t)(row0 + 64 + lane) * CTAGS + c0;
#pragma unroll
    for (int c = 0; c < 13; ++c) { eo0[c] = acc0[c]; eo1[c] = acc1[c]; }
}

// ---------------------------------------------------------------------------
// K2: serial Viterbi scan v5 — TWO batches per wave, interleaved independent
// recurrences (latency overlap); incremental quad-max (no a[52]); LDS state
// broadcast via uniform ds_read_b128 (R7-proven); zero barriers.
// ---------------------------------------------------------------------------
#define SCH  16                      // steps per chunk
#define SCQ  (SCH * CTAGS / 4)       // 208 float4 per chunk
#define NSCH (SEQL / SCH)            // 32 chunks

__global__ __launch_bounds__(64) void viterbi_scan2(
    const float* __restrict__ emit, const int* __restrict__ masks,
    const float* __restrict__ T, float* __restrict__ s_hist,
    float* __restrict__ out, int* __restrict__ btag)
{
    const int bA = blockIdx.x * 2;
    const int bB = bA + 1;
    const int to = threadIdx.x;
    const int toc = (to < CTAGS) ? to : (CTAGS - 1);

    __shared__ float eAb[2][SCH * CTAGS];   // 2 x 3328 B
    __shared__ float eBb[2][SCH * CTAGS];
    __shared__ int   mlA[SEQL], mlB[SEQL];  // 4 KB
    __shared__ __align__(16) float stA[64], stB[64];

    // T row in 13 named quads (shared by both batches)
    const float4* Tq = (const float4*)(T + (size_t)toc * CTAGS);
    const float4 tr0 = Tq[0],  tr1 = Tq[1],  tr2 = Tq[2],  tr3 = Tq[3];
    const float4 tr4 = Tq[4],  tr5 = Tq[5],  tr6 = Tq[6],  tr7 = Tq[7];
    const float4 tr8 = Tq[8],  tr9 = Tq[9],  tr10 = Tq[10], tr11 = Tq[11];
    const float4 tr12 = Tq[12];
    const float tstop = T[STOP_IDX * CTAGS + toc];

    const float4* eqA = (const float4*)(emit + (size_t)bA * SEQL * CTAGS);
    const float4* eqB = (const float4*)(emit + (size_t)bB * SEQL * CTAGS);
    const int* mbA = masks + (size_t)bA * SEQL;
    const int* mbB = masks + (size_t)bB * SEQL;
    float* sbA = s_hist + (size_t)bA * SEQL * CTAGS;
    float* sbB = s_hist + (size_t)bB * SEQL * CTAGS;

    // prologue: masks, chunk 0, state init
#pragma unroll
    for (int j = 0; j < 8; ++j) {
        mlA[to + 64 * j] = mbA[to + 64 * j];
        mlB[to + 64 * j] = mbB[to + 64 * j];
    }
#pragma unroll
    for (int j = 0; j < 4; ++j) {
        int idx = to + 64 * j;
        if (idx < SCQ) {
            *(float4*)&eAb[0][idx * 4] = eqA[idx];
            *(float4*)&eBb[0][idx * 4] = eqB[idx];
        }
    }
    stA[to] = (to == START_IDX) ? 0.f : -10000.f;
    stB[to] = (to == START_IDX) ? 0.f : -10000.f;

    float curA = (to == START_IDX) ? 0.f : -10000.f;
    float curB = curA;
    int cb = 0;

    for (int c = 0; c < NSCH; ++c) {
        // prefetch next chunk for both batches (consumed ~5k cycles later)
        float4 pA0, pA1, pA2, pA3, pB0, pB1, pB2, pB3;
        const int more = (c < NSCH - 1);
        if (more) {
            const float4* sA = eqA + (size_t)(c + 1) * SCQ;
            const float4* sB = eqB + (size_t)(c + 1) * SCQ;
            pA0 = sA[to]; pA1 = sA[to + 64]; pA2 = sA[to + 128];
            pB0 = sB[to]; pB1 = sB[to + 64]; pB2 = sB[to + 128];
            if (to < SCQ - 192) { pA3 = sA[to + 192]; pB3 = sB[to + 192]; }
        }

        for (int s = 0; s < SCH; ++s) {
            const int t = c * SCH + s;

            float eA = eAb[cb][s * CTAGS + toc];
            float eB = eBb[cb][s * CTAGS + toc];
            int   mA = mlA[t];
            int   mB = mlB[t];

            // store pre-update states
            if (to < CTAGS) {
                sbA[(size_t)t * CTAGS + to] = curA;
                sbB[(size_t)t * CTAGS + to] = curB;
            }

            // incremental quad-max over state+T for both batches
            float mxA = NEG_INF, mxB = NEG_INF;
#define QM(stv, q, trq, mx)                                                  \
            {                                                                \
                const float4 sq = *(const float4*)&stv[4 * q];               \
                float x0 = sq.x + trq.x, x1 = sq.y + trq.y;                  \
                float x2 = sq.z + trq.z, x3 = sq.w + trq.w;                  \
                mx = fmaxf(mx, fmaxf(fmaxf(x0, x1), fmaxf(x2, x3)));         \
            }
            QM(stA, 0, tr0, mxA)   QM(stB, 0, tr0, mxB)
            QM(stA, 1, tr1, mxA)   QM(stB, 1, tr1, mxB)
            QM(stA, 2, tr2, mxA)   QM(stB, 2, tr2, mxB)
            QM(stA, 3, tr3, mxA)   QM(stB, 3, tr3, mxB)
            QM(stA, 4, tr4, mxA)   QM(stB, 4, tr4, mxB)
            QM(stA, 5, tr5, mxA)   QM(stB, 5, tr5, mxB)
            QM(stA, 6, tr6, mxA)   QM(stB, 6, tr6, mxB)
            QM(stA, 7, tr7, mxA)   QM(stB, 7, tr7, mxB)
            QM(stA, 8, tr8, mxA)   QM(stB, 8, tr8, mxB)
            QM(stA, 9, tr9, mxA)   QM(stB, 9, tr9, mxB)
            QM(stA, 10, tr10, mxA) QM(stB, 10, tr10, mxB)
            QM(stA, 11, tr11, mxA) QM(stB, 11, tr11, mxB)
            QM(stA, 12, tr12, mxA) QM(stB, 12, tr12, mxB)
#undef QM

            curA = mA ? (mxA + eA) : curA;
            curB = mB ? (mxB + eB) : curB;

            // publish new states (single-wave in-order LDS)
            if (to < CTAGS) { stA[to] = curA; stB[to] = curB; }
        }

        if (more) {
            const int nb = cb ^ 1;
            *(float4*)&eAb[nb][to * 4]         = pA0;
            *(float4*)&eAb[nb][(to + 64) * 4]  = pA1;
            *(float4*)&eAb[nb][(to + 128) * 4] = pA2;
            *(float4*)&eBb[nb][to * 4]         = pB0;
            *(float4*)&eBb[nb][(to + 64) * 4]  = pB1;
            *(float4*)&eBb[nb][(to + 128) * 4] = pB2;
            if (to < SCQ - 192) {
                *(float4*)&eAb[nb][(to + 192) * 4] = pA3;
                *(float4*)&eBb[nb][(to + 192) * 4] = pB3;
            }
        }
        cb ^= 1;
    }

    // final argmax per batch (first-index tiebreak)
    float vA = (to < CTAGS) ? (curA + tstop) : NEG_INF;
    float vB = (to < CTAGS) ? (curB + tstop) : NEG_INF;
    int iA = to, iB = to;
#pragma unroll
    for (int s = 1; s < 64; s <<= 1) {
        float oA = __shfl_xor(vA, s);  int jA = __shfl_xor(iA, s);
        float oB = __shfl_xor(vB, s);  int jB = __shfl_xor(iB, s);
        if (oA > vA || (oA == vA && jA < iA)) { vA = oA; iA = jA; }
        if (oB > vB || (oB == vB && jB < iB)) { vB = oB; iB = jB; }
    }
    if (to == 0) {
        out[bA] = vA; btag[bA] = iA;
        out[bB] = vB; btag[bB] = iB;
    }
}

// ---------------------------------------------------------------------------
// K3: backpointers, parallel over (b,t). (unchanged, known-good)
// ---------------------------------------------------------------------------
#define PPW 16

__global__ __launch_bounds__(256) void bp_compute(
    const float* __restrict__ s_hist, const float* __restrict__ T,
    unsigned char* __restrict__ bp)
{
    const int lane = threadIdx.x & 63;
    const int wv   = __builtin_amdgcn_readfirstlane(threadIdx.x >> 6);
    const int toc  = (lane < CTAGS) ? lane : (CTAGS - 1);
    const int w    = blockIdx.x * 4 + wv;

    float Trow[CTAGS];
#pragma unroll
    for (int f = 0; f < CTAGS; ++f) Trow[f] = T[toc * CTAGS + f];

    for (int i = 0; i < PPW; ++i) {
        const int p = w * PPW + i;            // p = b*SEQL + t
        const float* sp = s_hist + (size_t)p * CTAGS;

        float a[CTAGS];
#pragma unroll
        for (int q = 0; q < 13; ++q) {
            float4 sv = *(const float4*)(sp + q * 4);
            a[q * 4 + 0] = sv.x + Trow[q * 4 + 0];
            a[q * 4 + 1] = sv.y + Trow[q * 4 + 1];
            a[q * 4 + 2] = sv.z + Trow[q * 4 + 2];
            a[q * 4 + 3] = sv.w + Trow[q * 4 + 3];
        }

        float l1[17];
#pragma unroll
        for (int j = 0; j < 17; ++j)
            l1[j] = fmaxf(fmaxf(a[3 * j], a[3 * j + 1]), a[3 * j + 2]);
        float l2[6];
#pragma unroll
        for (int j = 0; j < 5; ++j)
            l2[j] = fmaxf(fmaxf(l1[3 * j], l1[3 * j + 1]), l1[3 * j + 2]);
        l2[5] = fmaxf(fmaxf(l1[15], l1[16]), a[51]);
        const float m = fmaxf(fmaxf(fmaxf(l2[0], l2[1]), l2[2]),
                              fmaxf(fmaxf(l2[3], l2[4]), l2[5]));

        int c1[18];
#pragma unroll
        for (int j = 0; j < 17; ++j) {
            int x = (a[3 * j]     == m) ? (3 * j)     : 63;
            int y = (a[3 * j + 1] == m) ? (3 * j + 1) : 63;
            int z = (a[3 * j + 2] == m) ? (3 * j + 2) : 63;
            c1[j] = min(min(x, y), z);
        }
        c1[17] = (a[51] == m) ? 51 : 63;
        int c2[6];
#pragma unroll
        for (int j = 0; j < 6; ++j)
            c2[j] = min(min(c1[3 * j], c1[3 * j + 1]), c1[3 * j + 2]);
        const int idx = min(min(min(c2[0], c2[1]), c2[2]),
                            min(min(c2[3], c2[4]), c2[5]));

        if (lane < CTAGS)
            bp[(size_t)p * CTAGS + lane] = (unsigned char)idx;
    }
}

// ---------------------------------------------------------------------------
// K4: backtrack (unchanged, known-good).
// ---------------------------------------------------------------------------
__global__ __launch_bounds__(64) void viterbi_bt(
    const unsigned char* __restrict__ bp, const int* __restrict__ masks,
    const int* __restrict__ btag, float* __restrict__ out)
{
    const int b   = blockIdx.x;
    const int tid = threadIdx.x;

    __shared__ __align__(16) unsigned char bpl[SEQL * CTAGS];
    __shared__ int ml[SEQL];
    __shared__ unsigned char pathb[SEQL];

    const uint4* src = (const uint4*)(bp + (size_t)b * SEQL * CTAGS);
    for (int i = tid; i < SEQL * CTAGS / 16; i += 64)
        ((uint4*)bpl)[i] = src[i];
    for (int i = tid; i < SEQL; i += 64) ml[i] = masks[(size_t)b * SEQL + i];
    __syncthreads();

    int c = btag[b];
    if (tid == 0) pathb[SEQL - 1] = (unsigned char)c;
    for (int i = SEQL - 2; i >= 0; --i) {
        int nxt = bpl[(i + 1) * CTAGS + c];
        c = ml[i] ? nxt : c;
        if (tid == 0) pathb[i] = (unsigned char)c;
    }
    __syncthreads();

    float* po = out + BATCH + (size_t)b * SEQL;
#pragma unroll
    for (int i = 0; i < 8; ++i)
        po[i * 64 + tid] = (float)pathb[i * 64 + tid];
}

// ---------------------------------------------------------------------------
extern "C" void kernel_launch(void* const* d_in, const int* in_sizes, int n_in,
                              void* d_out, int out_size, void* d_ws, size_t ws_size,
                              hipStream_t stream)
{
    const float* features = (const float*)d_in[0];
    const int*   masks    = (const int*)d_in[1];
    const float* W        = (const float*)d_in[2];
    const float* bias     = (const float*)d_in[3];
    const float* T        = (const float*)d_in[4];

    float* out = (float*)d_out;

    // ws layout: emit/s_hist (13.63 MB, aliased: scan consumes emit[t] at
    // least 16 steps ahead of overwriting) | bp (3.41 MB) | btag.
    // WT (160 KB) aliases the bp region: dead before bp_compute writes.
    const size_t emit_bytes = (size_t)BATCH * SEQL * CTAGS * sizeof(float);
    const size_t bp_bytes   = (size_t)BATCH * SEQL * CTAGS;
    float*         emit   = (float*)d_ws;
    float*         s_hist = emit;
    unsigned char* bpws   = (unsigned char*)d_ws + emit_bytes;
    float*         WT     = (float*)bpws;
    int*           btag   = (int*)((unsigned char*)d_ws + emit_bytes + bp_bytes);

    wtrans<<<(FDIM * CTAGS + 255) / 256, 256, 0, stream>>>(W, WT);
    emit_gemm5<<<BATCH * SEQL / 128, 256, 0, stream>>>(features, WT, bias, emit);
    viterbi_scan2<<<BATCH / 2, 64, 0, stream>>>(emit, masks, T, s_hist, out, btag);
    bp_compute<<<BATCH * SEQL / (4 * PPW), 256, 0, stream>>>(s_hist, T, bpws);
    viterbi_bt<<<BATCH, 64, 0, stream>>>(bpws, masks, btag, out);
}